// Round 6
// baseline (289.865 us; speedup 1.0000x reference)
//
#include <hip/hip_runtime.h>

#define S_LEN 1024
#define HID   4544            // 71*64; K of both GEMMs
#define NH    71
#define NQKV  4672            // 73*64

typedef __attribute__((ext_vector_type(4))) float f32x4;
typedef __attribute__((ext_vector_type(4))) unsigned short u16x4;
typedef __attribute__((ext_vector_type(8))) unsigned short u16x8;
typedef __attribute__((ext_vector_type(8))) __bf16 bf16x8;

__device__ __forceinline__ bf16x8 as_bf(u16x8 v) { return __builtin_bit_cast(bf16x8, v); }

__device__ __forceinline__ unsigned short f2bf(float f) {
    unsigned u = __builtin_bit_cast(unsigned, f);
    return (unsigned short)((u + 0x7FFFu + ((u >> 16) & 1u)) >> 16);  // RNE
}
__device__ __forceinline__ float bf2f(unsigned short u) {
    return __builtin_bit_cast(float, (unsigned)u << 16);
}
__device__ __forceinline__ unsigned pk2(float a, float b) {   // packed bf16x2, RNE
    return (unsigned)f2bf(a) | ((unsigned)f2bf(b) << 16);
}
__device__ __forceinline__ void gload16(const void* g, void* l) {
    __builtin_amdgcn_global_load_lds((const __attribute__((address_space(1))) unsigned int*)g,
                                     (__attribute__((address_space(3))) unsigned int*)l,
                                     16, 0, 0);
}

// ---------- fp32 -> bf16 elementwise (x) ----------
__global__ __launch_bounds__(256) void cvt_x_kernel(const float4* __restrict__ x,
                                                    ushort4* __restrict__ y) {
    int i = blockIdx.x * 256 + threadIdx.x;
    float4 v = x[i];
    ushort4 r;
    r.x = f2bf(v.x); r.y = f2bf(v.y); r.z = f2bf(v.z); r.w = f2bf(v.w);
    y[i] = r;
}

// ---------- fp32 (K x N) -> bf16 transposed (N x K); N % 64 == 0 ----------
__global__ __launch_bounds__(256) void cvt_wT_kernel(const float* __restrict__ w,
                                                     unsigned short* __restrict__ wt,
                                                     int K, int N) {
    __shared__ float t[64][65];
    int n0 = blockIdx.x * 64, k0 = blockIdx.y * 64;
    int tx = threadIdx.x & 15, ty = threadIdx.x >> 4;   // 16 x 16
#pragma unroll
    for (int r = 0; r < 64; r += 16) {
        int k = k0 + ty + r;
        float4 v = *(const float4*)&w[(size_t)k * N + n0 + tx * 4];
        t[ty + r][tx * 4 + 0] = v.x;
        t[ty + r][tx * 4 + 1] = v.y;
        t[ty + r][tx * 4 + 2] = v.z;
        t[ty + r][tx * 4 + 3] = v.w;
    }
    __syncthreads();
    int nr = threadIdx.x >> 2;           // output row n (0..63)
    int kq = (threadIdx.x & 3) * 16;     // 16 k-values per thread
    unsigned short tmp[16];
#pragma unroll
    for (int z = 0; z < 16; z++) tmp[z] = f2bf(t[kq + z][nr]);
    u16x8* dst = (u16x8*)&wt[(size_t)(n0 + nr) * K + k0 + kq];
    dst[0] = *(const u16x8*)&tmp[0];
    dst[1] = *(const u16x8*)&tmp[8];
}

// ---------- RoPE cos/sin table: [1024][32] fp32 each ----------
__global__ void rope_table_kernel(float* __restrict__ cs, float* __restrict__ sn) {
    int s = blockIdx.x, i = threadIdx.x;     // 32 threads
    float inv = powf(10000.0f, -(2.0f * (float)i) / 64.0f);
    float f = (float)s * inv;
    cs[s * 32 + i] = cosf(f);
    sn[s * 32 + i] = sinf(f);
}

// ---------- bf16 MFMA GEMM, split-K=2, BM=128 BN=64 BK=64, 2-phase dbuf ----------
// grid = 16 * (N/64).  XCD-ownership: xcd = p&7 owns (m-pair = xcd>>1, split =
// xcd&1); within XCD, n sweeps slowly with m2 innermost -> A working set per
// XCD = 2 slices x half-K = 1.16MB (stays L2-hot); each B half-panel streamed
// by 4 XCDs only.  Writes fp32 partials P[split][S_LEN][N].
__global__ __launch_bounds__(256, 3) void gemm_split_kernel(
        const unsigned short* __restrict__ A, const unsigned short* __restrict__ BT,
        float* __restrict__ P, int N) {
    __shared__ unsigned short As[2][128 * 64];   // 16KB each
    __shared__ unsigned short Bs[2][64 * 64];    // 8KB each
    int p = blockIdx.x;
    int xcd = p & 7, idx = p >> 3;
    int split = xcd & 1, mp = xcd >> 1;
    int nbk = idx >> 1, m2 = idx & 1;
    int m0 = (mp * 2 + m2) * 128, n0 = nbk * 64;
    int s_begin = split ? 36 : 0;
    int s_cnt   = split ? 35 : 36;               // 71 BK=64 chunks total (K=4544)
    int t = threadIdx.x;
    int wv = t >> 6, lane = t & 63, lr = lane & 15, lg = lane >> 4;
    int mw = wv * 32;
    int sw = lr & 7;
    int srow = t >> 3, sc16 = t & 7;     // staging: row-base, col16

    f32x4 acc[2][4];
#pragma unroll
    for (int mi = 0; mi < 2; mi++)
#pragma unroll
        for (int ni = 0; ni < 4; ni++) acc[mi][ni] = (f32x4)0.0f;

    const char* Ab = (const char*)A;
    const char* Bb = (const char*)BT;
    size_t rs = (size_t)HID * 2;

    auto stage = [&](int step, int buf) {
        size_t kb = (size_t)step * 128;   // 64 elems * 2B
#pragma unroll
        for (int i = 0; i < 4; i++) {     // A: 128 rows
            int row = i * 32 + srow;
            int csrc = sc16 ^ (row & 7);
            gload16(Ab + (size_t)(m0 + row) * rs + kb + csrc * 16,
                    (char*)As[buf] + (i * 256 + t) * 16);
        }
#pragma unroll
        for (int i = 0; i < 2; i++) {     // B: 64 rows
            int row = i * 32 + srow;
            int csrc = sc16 ^ (row & 7);
            gload16(Bb + (size_t)(n0 + row) * rs + kb + csrc * 16,
                    (char*)Bs[buf] + (i * 256 + t) * 16);
        }
    };

    stage(s_begin, 0);
    __syncthreads();
    for (int s = 0; s < s_cnt; ++s) {
        int cur = s & 1;
        if (s + 1 < s_cnt) stage(s_begin + s + 1, cur ^ 1);
        bf16x8 af[2][2], bfr[4][2];
#pragma unroll
        for (int mi = 0; mi < 2; mi++)
#pragma unroll
            for (int kk = 0; kk < 2; kk++) {
                int row = mw + mi * 16 + lr;
                af[mi][kk] = as_bf(*(const u16x8*)&As[cur][row * 64 + (((kk * 4 + lg) ^ sw) << 3)]);
            }
#pragma unroll
        for (int ni = 0; ni < 4; ni++)
#pragma unroll
            for (int kk = 0; kk < 2; kk++) {
                int row = ni * 16 + lr;
                bfr[ni][kk] = as_bf(*(const u16x8*)&Bs[cur][row * 64 + (((kk * 4 + lg) ^ sw) << 3)]);
            }
#pragma unroll
        for (int mi = 0; mi < 2; mi++)
#pragma unroll
            for (int ni = 0; ni < 4; ni++) {
                acc[mi][ni] = __builtin_amdgcn_mfma_f32_16x16x32_bf16(af[mi][0], bfr[ni][0], acc[mi][ni], 0, 0, 0);
                acc[mi][ni] = __builtin_amdgcn_mfma_f32_16x16x32_bf16(af[mi][1], bfr[ni][1], acc[mi][ni], 0, 0, 0);
            }
        __syncthreads();
    }

    float* C = P + (size_t)split * S_LEN * N;
#pragma unroll
    for (int mi = 0; mi < 2; mi++)
#pragma unroll
        for (int ni = 0; ni < 4; ni++) {
            int col = n0 + ni * 16 + lr;
#pragma unroll
            for (int i = 0; i < 4; i++) {
                int row = m0 + mw + mi * 16 + 4 * lg + i;
                C[(size_t)row * N + col] = acc[mi][ni][i];
            }
        }
}

// ---------- QKV reduce: sum split-K partials + RoPE + scatter q/k/v ----------
// grid (256, 73), block 256 (4 s-values per block).
__global__ __launch_bounds__(256) void qkv_reduce_kernel(
        const float* __restrict__ P1, const float* __restrict__ cs,
        const float* __restrict__ sn, unsigned short* __restrict__ qb,
        unsigned short* __restrict__ kr, unsigned short* __restrict__ vt) {
    const size_t HALF = (size_t)S_LEN * NQKV;
    int t = threadIdx.x;
    int s = blockIdx.x * 4 + (t >> 6);
    int hh = blockIdx.y, d = t & 63;
    size_t base = (size_t)s * NQKV + hh * 64;
    if (hh == 72) {
        vt[(size_t)d * S_LEN + s] = f2bf(P1[base + d] + P1[HALF + base + d]);
        return;
    }
    int i = d & 31;
    float x  = P1[base + d]        + P1[HALF + base + d];
    float xo = P1[base + (d ^ 32)] + P1[HALF + base + (d ^ 32)];
    float c = cs[s * 32 + i], g = sn[s * 32 + i];
    float r = x * c + ((d < 32) ? -xo : xo) * g;
    if (hh == 71) kr[s * 64 + d] = f2bf(r);
    else          qb[(size_t)s * HID + hh * 64 + d] = f2bf(r * 0.125f);  // fold 1/sqrt(64)
}

// ---------- dense reduce: out = Pa + Pb (fp32) ----------
__global__ __launch_bounds__(256) void dense_reduce_kernel(
        const f32x4* __restrict__ Pa, const f32x4* __restrict__ Pb,
        f32x4* __restrict__ out) {
    int i = blockIdx.x * 256 + threadIdx.x;
    out[i] = Pa[i] + Pb[i];
}

// ---------- flash attention (MQA), split-K, LDS-shared K/V ----------
// grid (40, 71), block 256. Block = (head, chunk c, 4 q-tiles j0..j0+3).
// Wave wv: j = j0+wv, 16 q-rows, k-range [256c, min((j+1)*16, 256c+256)).
// nch(j)=1 -> write ctx directly; else unnormalized partials (bf16 O + f32 m,l).
__global__ __launch_bounds__(256, 3) void attn_kernel(
        const unsigned short* __restrict__ qb, const unsigned short* __restrict__ kr,
        const unsigned short* __restrict__ vt, unsigned short* __restrict__ ctx,
        unsigned short* __restrict__ Opart, float2* __restrict__ MLpart) {
    __shared__ unsigned short Ks[2][64 * 64];
    __shared__ unsigned short Vs[2][64 * 64];
    __shared__ unsigned short Pl[4][16 * 72];
    int h = blockIdx.y;
    int u = blockIdx.x;
    int c, j0;
    if (u < 16)      { c = 0; j0 = u * 4; }
    else if (u < 28) { c = 1; j0 = 16 + (u - 16) * 4; }
    else if (u < 36) { c = 2; j0 = 32 + (u - 28) * 4; }
    else             { c = 3; j0 = 48 + (u - 36) * 4; }
    int t = threadIdx.x, wv = t >> 6, lane = t & 63, lr = lane & 15, lg = lane >> 4;
    int j = j0 + wv;
    int qs = j * 16 + lr;
    int k_lo = c * 256;
    int kend_w   = min((j + 1) * 16, k_lo + 256);
    int kend_max = min((j0 + 4) * 16, k_lo + 256);
    int nt = (kend_max - k_lo) >> 6;
    int nch = (j >> 4) + 1;
    int srow = t >> 3, sc16 = t & 7, sw = lr & 7;

    auto stage = [&](int ti, int buf) {
        size_t kbase = (size_t)(k_lo + ti * 64);
#pragma unroll
        for (int i = 0; i < 2; i++) {
            int row = i * 32 + srow;
            int csrc = sc16 ^ (row & 7);
            gload16((const char*)kr + (kbase + row) * 128 + csrc * 16,
                    (char*)Ks[buf] + (i * 256 + t) * 16);
        }
#pragma unroll
        for (int i = 0; i < 2; i++) {
            int row = i * 32 + srow;
            int csrc = sc16 ^ (row & 7);
            gload16((const char*)vt + (size_t)row * 2048 + kbase * 2 + csrc * 16,
                    (char*)Vs[buf] + (i * 256 + t) * 16);
        }
    };

    bf16x8 qf[2];
#pragma unroll
    for (int dc = 0; dc < 2; dc++)
        qf[dc] = as_bf(*(const u16x8*)&qb[(size_t)qs * HID + h * 64 + dc * 32 + 8 * lg]);

    float m_i = -1e30f, l_i = 0.0f;
    f32x4 o[4];
#pragma unroll
    for (int d4 = 0; d4 < 4; d4++) o[d4] = (f32x4)0.0f;

    stage(0, 0);
    __syncthreads();

    for (int ti = 0; ti < nt; ti++) {
        int cur = ti & 1;
        if (ti + 1 < nt) stage(ti + 1, cur ^ 1);
        int k0 = k_lo + ti * 64;
        if (k0 < kend_w) {
            f32x4 st[4];
#pragma unroll
            for (int nc = 0; nc < 4; nc++) st[nc] = (f32x4)0.0f;
#pragma unroll
            for (int nc = 0; nc < 4; nc++) {
                int krow = nc * 16 + lr;
#pragma unroll
                for (int dc = 0; dc < 2; dc++) {
                    bf16x8 kf = as_bf(*(const u16x8*)&Ks[cur][krow * 64 + (((dc * 4 + lg) ^ sw) << 3)]);
                    st[nc] = __builtin_amdgcn_mfma_f32_16x16x32_bf16(kf, qf[dc], st[nc], 0, 0, 0);
                }
            }
            bool needmask = (k0 + 64 > j * 16);
            float mx = -1e30f;
            if (needmask) {
#pragma unroll
                for (int nc = 0; nc < 4; nc++)
#pragma unroll
                    for (int i = 0; i < 4; i++) {
                        int ks = k0 + nc * 16 + 4 * lg + i;
                        float v = (ks <= qs) ? st[nc][i] : -1e30f;
                        st[nc][i] = v;
                        mx = fmaxf(mx, v);
                    }
            } else {
#pragma unroll
                for (int nc = 0; nc < 4; nc++)
#pragma unroll
                    for (int i = 0; i < 4; i++) mx = fmaxf(mx, st[nc][i]);
            }
            mx = fmaxf(mx, __shfl_xor(mx, 16));
            mx = fmaxf(mx, __shfl_xor(mx, 32));
            // T13 defer-max: skip rescale while max grows by <= 8
            if (!__all(mx <= m_i + 8.0f)) {
                float mn = fmaxf(m_i, mx);
                float so = __expf(m_i - mn);
                l_i *= so;
#pragma unroll
                for (int d4 = 0; d4 < 4; d4++)
#pragma unroll
                    for (int i = 0; i < 4; i++) o[d4][i] *= so;
                m_i = mn;
            }
            float ps = 0.0f;
#pragma unroll
            for (int nc = 0; nc < 4; nc++)
#pragma unroll
                for (int i = 0; i < 4; i++) {
                    float v = st[nc][i];
                    float e = (!needmask || v > -1e29f) ? __expf(v - m_i) : 0.0f;
                    st[nc][i] = e;
                    ps += e;
                }
            ps += __shfl_xor(ps, 16);
            ps += __shfl_xor(ps, 32);
            l_i += ps;
            // P^T (lane-local) -> Pl[q=lr][k] (pad 72: conflict-free)
#pragma unroll
            for (int nc = 0; nc < 4; nc++) {
                *(unsigned*)&Pl[wv][lr * 72 + nc * 16 + 4 * lg]     = pk2(st[nc][0], st[nc][1]);
                *(unsigned*)&Pl[wv][lr * 72 + nc * 16 + 4 * lg + 2] = pk2(st[nc][2], st[nc][3]);
            }
            bf16x8 pb[2];
#pragma unroll
            for (int kk = 0; kk < 2; kk++)
                pb[kk] = as_bf(*(const u16x8*)&Pl[wv][lr * 72 + kk * 32 + 8 * lg]);
#pragma unroll
            for (int d4 = 0; d4 < 4; d4++) {
                int vrow = d4 * 16 + lr;
#pragma unroll
                for (int kk = 0; kk < 2; kk++) {
                    bf16x8 vf = as_bf(*(const u16x8*)&Vs[cur][vrow * 64 + (((kk * 4 + lg) ^ sw) << 3)]);
                    o[d4] = __builtin_amdgcn_mfma_f32_16x16x32_bf16(vf, pb[kk], o[d4], 0, 0, 0);
                }
            }
        }
        __syncthreads();
    }

    if (nch == 1) {
        float linv = 1.0f / l_i;
#pragma unroll
        for (int d4 = 0; d4 < 4; d4++) {
            u16x4 pk;
#pragma unroll
            for (int i = 0; i < 4; i++) pk[i] = f2bf(o[d4][i] * linv);
            *(u16x4*)&ctx[(size_t)qs * HID + h * 64 + d4 * 16 + 4 * lg] = pk;
        }
    } else {
        int pi = (h * 48 + (j - 16)) * 4 + c;
#pragma unroll
        for (int d4 = 0; d4 < 4; d4++) {
            u16x4 pk;
#pragma unroll
            for (int i = 0; i < 4; i++) pk[i] = f2bf(o[d4][i]);
            *(u16x4*)&Opart[(size_t)pi * 1024 + lr * 64 + d4 * 16 + 4 * lg] = pk;
        }
        if (lg == 0) MLpart[pi * 16 + lr] = make_float2(m_i, l_i);
    }
}

// ---------- split-K merge: one wave per (h, j>=16) ----------
__global__ __launch_bounds__(256) void merge_kernel(
        const unsigned short* __restrict__ Opart, const float2* __restrict__ MLpart,
        unsigned short* __restrict__ ctx) {
    int mu = blockIdx.x * 4 + (threadIdx.x >> 6);
    int lane = threadIdx.x & 63;
    int h = mu / 48, jj = mu % 48, j = 16 + jj;
    int nch = (j >> 4) + 1;
    int base = (h * 48 + jj) * 4;
    for (int q = 0; q < 16; q++) {
        float m[4], l[4], w[4];
        float M = -1e30f;
        for (int c = 0; c < nch; c++) {
            float2 ml = MLpart[(base + c) * 16 + q];
            m[c] = ml.x; l[c] = ml.y;
            M = fmaxf(M, m[c]);
        }
        float L = 0.0f;
        for (int c = 0; c < nch; c++) { w[c] = __expf(m[c] - M); L += l[c] * w[c]; }
        float acc = 0.0f;
        for (int c = 0; c < nch; c++)
            acc += w[c] * bf2f(Opart[(size_t)(base + c) * 1024 + q * 64 + lane]);
        ctx[(size_t)(j * 16 + q) * HID + h * 64 + lane] = f2bf(acc / L);
    }
}

extern "C" void kernel_launch(void* const* d_in, const int* in_sizes, int n_in,
                              void* d_out, int out_size, void* d_ws, size_t ws_size,
                              hipStream_t stream) {
    const float* hs      = (const float*)d_in[0];
    // d_in[1] = attention_mask (analytic causal mask used instead)
    const float* qkv_w   = (const float*)d_in[2];
    const float* dense_w = (const float*)d_in[3];
    float* out = (float*)d_out;

    char* ws = (char*)d_ws;
    size_t off = 0;
    auto alloc = [&](size_t bytes) -> void* {
        void* p = ws + off;
        off += (bytes + 255) & ~(size_t)255;
        return p;
    };
    unsigned short* x_bf   = (unsigned short*)alloc((size_t)S_LEN * HID * 2);    // 9.3 MB
    unsigned short* wqkvT  = (unsigned short*)alloc((size_t)NQKV * HID * 2);     // 42.5 MB
    unsigned short* q_bf   = (unsigned short*)alloc((size_t)S_LEN * HID * 2);    // 9.3 MB
    unsigned short* k_rope = (unsigned short*)alloc((size_t)S_LEN * 64 * 2);
    unsigned short* v_t    = (unsigned short*)alloc((size_t)64 * S_LEN * 2);
    unsigned short* ctx    = (unsigned short*)alloc((size_t)S_LEN * HID * 2);    // 9.3 MB
    unsigned short* wdT    = (unsigned short*)alloc((size_t)HID * HID * 2);      // 41.3 MB
    float*          cs_t   = (float*)alloc((size_t)S_LEN * 32 * 4);
    float*          sn_t   = (float*)alloc((size_t)S_LEN * 32 * 4);
    (void)ws_size;   // ~112 MB
    // Aliases (lifetimes disjoint, stream-serialized):
    //  P1 (QKV fp32 partials, 38.3MB) overlays wdT (written later by cvt_wT dense)
    //  Opart/MLpart (29.6MB) overlay wqkvT (dead after QKV GEMM)
    //  P2 (dense fp32 partials, 37.2MB) overlays wqkvT too (after merge)
    float*          P1     = (float*)wdT;
    unsigned short* Opart  = wqkvT;
    float2*         MLpart = (float2*)((char*)wqkvT + (size_t)71 * 48 * 4 * 1024 * 2);
    float*          P2     = (float*)wqkvT;

    cvt_x_kernel<<<dim3(S_LEN * HID / 1024), dim3(256), 0, stream>>>(
        (const float4*)hs, (ushort4*)x_bf);
    cvt_wT_kernel<<<dim3(NQKV / 64, HID / 64), dim3(256), 0, stream>>>(
        qkv_w, wqkvT, HID, NQKV);
    rope_table_kernel<<<dim3(S_LEN), dim3(32), 0, stream>>>(cs_t, sn_t);

    // QKV GEMM (split-K=2): P1[2][1024][4672]
    gemm_split_kernel<<<dim3(16 * NQKV / 64), dim3(256), 0, stream>>>(
        x_bf, wqkvT, P1, NQKV);
    // reduce + RoPE + scatter q/k/v
    qkv_reduce_kernel<<<dim3(S_LEN / 4, NQKV / 64), dim3(256), 0, stream>>>(
        P1, cs_t, sn_t, q_bf, k_rope, v_t);

    // dense weight conversion (after P1 is dead — P1 aliases wdT)
    cvt_wT_kernel<<<dim3(HID / 64, HID / 64), dim3(256), 0, stream>>>(
        dense_w, wdT, HID, HID);

    attn_kernel<<<dim3(40, NH), dim3(256), 0, stream>>>(
        q_bf, k_rope, v_t, ctx, Opart, MLpart);
    merge_kernel<<<dim3(NH * 48 / 4), dim3(256), 0, stream>>>(Opart, MLpart, ctx);

    // dense GEMM (split-K=2): P2[2][1024][4544], then reduce to out
    gemm_split_kernel<<<dim3(16 * HID / 64), dim3(256), 0, stream>>>(
        ctx, wdT, P2, HID);
    dense_reduce_kernel<<<dim3(S_LEN * HID / 1024), dim3(256), 0, stream>>>(
        (const f32x4*)P2, (const f32x4*)(P2 + (size_t)S_LEN * HID), (f32x4*)out);
}

// Round 7
// 243.169 us; speedup vs baseline: 1.1920x; 1.1920x over previous
//
#include <hip/hip_runtime.h>

#define S_LEN 1024
#define HID   4544            // 71*64; K of both GEMMs
#define NH    71
#define NQKV  4672            // 73*64

typedef __attribute__((ext_vector_type(4))) float f32x4;
typedef __attribute__((ext_vector_type(4))) unsigned short u16x4;
typedef __attribute__((ext_vector_type(8))) unsigned short u16x8;
typedef __attribute__((ext_vector_type(8))) __bf16 bf16x8;

__device__ __forceinline__ bf16x8 as_bf(u16x8 v) { return __builtin_bit_cast(bf16x8, v); }

__device__ __forceinline__ unsigned short f2bf(float f) {
    unsigned u = __builtin_bit_cast(unsigned, f);
    return (unsigned short)((u + 0x7FFFu + ((u >> 16) & 1u)) >> 16);  // RNE
}
__device__ __forceinline__ float bf2f(unsigned short u) {
    return __builtin_bit_cast(float, (unsigned)u << 16);
}
__device__ __forceinline__ unsigned pk2(float a, float b) {   // packed bf16x2, RNE
    return (unsigned)f2bf(a) | ((unsigned)f2bf(b) << 16);
}
__device__ __forceinline__ void gload16(const void* g, void* l) {
    __builtin_amdgcn_global_load_lds((const __attribute__((address_space(1))) unsigned int*)g,
                                     (__attribute__((address_space(3))) unsigned int*)l,
                                     16, 0, 0);
}

// ---------- fp32 -> bf16 elementwise (x) ----------
__global__ __launch_bounds__(256) void cvt_x_kernel(const float4* __restrict__ x,
                                                    ushort4* __restrict__ y) {
    int i = blockIdx.x * 256 + threadIdx.x;
    float4 v = x[i];
    ushort4 r;
    r.x = f2bf(v.x); r.y = f2bf(v.y); r.z = f2bf(v.z); r.w = f2bf(v.w);
    y[i] = r;
}

// ---------- fp32 (K x N) -> bf16 transposed (N x K); N % 64 == 0 ----------
__global__ __launch_bounds__(256) void cvt_wT_kernel(const float* __restrict__ w,
                                                     unsigned short* __restrict__ wt,
                                                     int K, int N) {
    __shared__ float t[64][65];
    int n0 = blockIdx.x * 64, k0 = blockIdx.y * 64;
    int tx = threadIdx.x & 15, ty = threadIdx.x >> 4;   // 16 x 16
#pragma unroll
    for (int r = 0; r < 64; r += 16) {
        int k = k0 + ty + r;
        float4 v = *(const float4*)&w[(size_t)k * N + n0 + tx * 4];
        t[ty + r][tx * 4 + 0] = v.x;
        t[ty + r][tx * 4 + 1] = v.y;
        t[ty + r][tx * 4 + 2] = v.z;
        t[ty + r][tx * 4 + 3] = v.w;
    }
    __syncthreads();
    int nr = threadIdx.x >> 2;           // output row n (0..63)
    int kq = (threadIdx.x & 3) * 16;     // 16 k-values per thread
    unsigned short tmp[16];
#pragma unroll
    for (int z = 0; z < 16; z++) tmp[z] = f2bf(t[kq + z][nr]);
    u16x8* dst = (u16x8*)&wt[(size_t)(n0 + nr) * K + k0 + kq];
    dst[0] = *(const u16x8*)&tmp[0];
    dst[1] = *(const u16x8*)&tmp[8];
}

// ---------- RoPE cos/sin table: [1024][32] fp32 each ----------
__global__ void rope_table_kernel(float* __restrict__ cs, float* __restrict__ sn) {
    int s = blockIdx.x, i = threadIdx.x;     // 32 threads
    float inv = powf(10000.0f, -(2.0f * (float)i) / 64.0f);
    float f = (float)s * inv;
    cs[s * 32 + i] = cosf(f);
    sn[s * 32 + i] = sinf(f);
}

// ---------- bf16 MFMA GEMM, BM=128 BN=64 BK=64, depth-2 counted-vmcnt pipe ----------
// 1-D grid, XCD-chunked remap (l = (p&7)*per + p>>3, m fastest): B panel L2 reuse.
// Pipeline: stages s and s+1 always in flight; per step wait vmcnt(6) (stage s
// landed, s+1 still flying), raw barrier, ds_read frags, lgkmcnt(0), barrier,
// issue stage(s+2) into the just-read buffer, MFMA. No vmcnt(0) drain in loop.
// EPI 0: C fp32.  EPI 1: QKV epilogue — rope q (x1/8) / rope k / v transposed.
template<int EPI>
__global__ __launch_bounds__(256, 3) void gemm_bt_kernel(
        const unsigned short* __restrict__ A, const unsigned short* __restrict__ BT,
        void* __restrict__ Cout, const float* __restrict__ cs_t,
        const float* __restrict__ sn_t, unsigned short* __restrict__ k_out,
        unsigned short* __restrict__ v_out, int K, int ldc) {
    __shared__ unsigned short As[2][128 * 64];   // 16KB each
    __shared__ unsigned short Bs[2][64 * 64];    // 8KB each
    int p = blockIdx.x;
    int per = gridDim.x >> 3;                    // blocks per XCD (grid % 8 == 0)
    int l = (p & 7) * per + (p >> 3);
    int m0 = (l & 7) * 128, ni_b = l >> 3, n0 = ni_b * 64;
    int t = threadIdx.x;
    int wv = t >> 6, lane = t & 63, lr = lane & 15, lg = lane >> 4;
    int mw = wv * 32;
    int sw = lr & 7;
    int srow = t >> 3, sc16 = t & 7;     // staging: row-base, col16

    f32x4 acc[2][4];
#pragma unroll
    for (int mi = 0; mi < 2; mi++)
#pragma unroll
        for (int ni = 0; ni < 4; ni++) acc[mi][ni] = (f32x4)0.0f;

    const char* Ab = (const char*)A;
    const char* Bb = (const char*)BT;
    size_t rs = (size_t)K * 2;

    auto stage = [&](int step, int buf) {        // 6 global_load_lds per thread
        size_t kb = (size_t)step * 128;          // 64 elems * 2B
#pragma unroll
        for (int i = 0; i < 4; i++) {            // A: 128 rows
            int row = i * 32 + srow;
            int csrc = sc16 ^ (row & 7);
            gload16(Ab + (size_t)(m0 + row) * rs + kb + csrc * 16,
                    (char*)As[buf] + (i * 256 + t) * 16);
        }
#pragma unroll
        for (int i = 0; i < 2; i++) {            // B: 64 rows
            int row = i * 32 + srow;
            int csrc = sc16 ^ (row & 7);
            gload16(Bb + (size_t)(n0 + row) * rs + kb + csrc * 16,
                    (char*)Bs[buf] + (i * 256 + t) * 16);
        }
    };

    int nsteps = K >> 6;
    stage(0, 0);
    if (nsteps > 1) stage(1, 1);
    for (int s = 0; s < nsteps; ++s) {
        int cur = s & 1;
        if (s + 1 < nsteps) { asm volatile("s_waitcnt vmcnt(6)" ::: "memory"); }
        else                { asm volatile("s_waitcnt vmcnt(0)" ::: "memory"); }
        __builtin_amdgcn_s_barrier();            // stage(s) fully landed (all waves)
        bf16x8 af[2][2], bfr[4][2];
#pragma unroll
        for (int mi = 0; mi < 2; mi++)
#pragma unroll
            for (int kk = 0; kk < 2; kk++) {
                int row = mw + mi * 16 + lr;
                af[mi][kk] = as_bf(*(const u16x8*)&As[cur][row * 64 + (((kk * 4 + lg) ^ sw) << 3)]);
            }
#pragma unroll
        for (int ni = 0; ni < 4; ni++)
#pragma unroll
            for (int kk = 0; kk < 2; kk++) {
                int row = ni * 16 + lr;
                bfr[ni][kk] = as_bf(*(const u16x8*)&Bs[cur][row * 64 + (((kk * 4 + lg) ^ sw) << 3)]);
            }
        asm volatile("s_waitcnt lgkmcnt(0)" ::: "memory");
        __builtin_amdgcn_s_barrier();            // all waves done reading buf cur
        if (s + 2 < nsteps) stage(s + 2, cur);   // overwrite buf cur
#pragma unroll
        for (int mi = 0; mi < 2; mi++)
#pragma unroll
            for (int ni = 0; ni < 4; ni++) {
                acc[mi][ni] = __builtin_amdgcn_mfma_f32_16x16x32_bf16(af[mi][0], bfr[ni][0], acc[mi][ni], 0, 0, 0);
                acc[mi][ni] = __builtin_amdgcn_mfma_f32_16x16x32_bf16(af[mi][1], bfr[ni][1], acc[mi][ni], 0, 0, 0);
            }
    }

    if (EPI == 0) {
        float* C = (float*)Cout;
#pragma unroll
        for (int mi = 0; mi < 2; mi++)
#pragma unroll
            for (int ni = 0; ni < 4; ni++) {
                int col = n0 + ni * 16 + lr;
#pragma unroll
                for (int i = 0; i < 4; i++) {
                    int row = m0 + mw + mi * 16 + 4 * lg + i;
                    C[(size_t)row * ldc + col] = acc[mi][ni][i];
                }
            }
    } else {
        int hh = ni_b;
        if (hh == 72) {                       // v: write transposed [d][1024]
#pragma unroll
            for (int mi = 0; mi < 2; mi++)
#pragma unroll
                for (int ni = 0; ni < 4; ni++) {
                    int d = ni * 16 + lr;
                    int s0 = m0 + mw + mi * 16 + 4 * lg;
                    u16x4 pk;
#pragma unroll
                    for (int i = 0; i < 4; i++) pk[i] = f2bf(acc[mi][ni][i]);
                    *(u16x4*)&v_out[(size_t)d * S_LEN + s0] = pk;
                }
        } else {                              // q (hh<71) / k (hh==71): rope
            unsigned short* qb = (unsigned short*)Cout;
            float qscale = (hh < 71) ? 0.125f : 1.0f;
#pragma unroll
            for (int mi = 0; mi < 2; mi++)
#pragma unroll
                for (int i = 0; i < 4; i++) {
                    int s = m0 + mw + mi * 16 + 4 * lg + i;
                    float c0 = cs_t[s * 32 + lr],      g0 = sn_t[s * 32 + lr];
                    float c1 = cs_t[s * 32 + 16 + lr], g1 = sn_t[s * 32 + 16 + lr];
#pragma unroll
                    for (int ni = 0; ni < 4; ni++) {
                        float x  = acc[mi][ni][i];
                        float xp = acc[mi][ni ^ 2][i];
                        float c = (ni & 1) ? c1 : c0;
                        float g = (ni & 1) ? g1 : g0;
                        float r = (ni < 2) ? (x * c - xp * g) : (x * c + xp * g);
                        r *= qscale;
                        int d = ni * 16 + lr;
                        if (hh < 71) qb[(size_t)s * HID + hh * 64 + d] = f2bf(r);
                        else         k_out[(size_t)s * 64 + d] = f2bf(r);
                    }
                }
        }
    }
}

// ---------- flash attention (MQA), split-K, LDS-shared K/V, counted-vmcnt ----------
// grid (40, 71), block 256. Block = (head, chunk c, 4 q-tiles j0..j0+3).
// Wave wv: j = j0+wv, 16 q-rows, k-range [256c, min((j+1)*16, 256c+256)).
// nch(j)=1 -> write ctx directly; else unnormalized partials (bf16 O + f32 m,l).
__global__ __launch_bounds__(256, 3) void attn_kernel(
        const unsigned short* __restrict__ qb, const unsigned short* __restrict__ kr,
        const unsigned short* __restrict__ vt, unsigned short* __restrict__ ctx,
        unsigned short* __restrict__ Opart, float2* __restrict__ MLpart) {
    __shared__ unsigned short Ks[2][64 * 64];
    __shared__ unsigned short Vs[2][64 * 64];
    __shared__ unsigned short Pl[4][16 * 72];
    int h = blockIdx.y;
    int u = blockIdx.x;
    int c, j0;
    if (u < 16)      { c = 0; j0 = u * 4; }
    else if (u < 28) { c = 1; j0 = 16 + (u - 16) * 4; }
    else if (u < 36) { c = 2; j0 = 32 + (u - 28) * 4; }
    else             { c = 3; j0 = 48 + (u - 36) * 4; }
    int t = threadIdx.x, wv = t >> 6, lane = t & 63, lr = lane & 15, lg = lane >> 4;
    int j = j0 + wv;
    int qs = j * 16 + lr;
    int k_lo = c * 256;
    int kend_w   = min((j + 1) * 16, k_lo + 256);
    int kend_max = min((j0 + 4) * 16, k_lo + 256);
    int nt = (kend_max - k_lo) >> 6;
    int nch = (j >> 4) + 1;
    int srow = t >> 3, sc16 = t & 7, sw = lr & 7;

    auto stage = [&](int ti, int buf) {          // 4 global_load_lds per thread
        size_t kbase = (size_t)(k_lo + ti * 64);
#pragma unroll
        for (int i = 0; i < 2; i++) {
            int row = i * 32 + srow;
            int csrc = sc16 ^ (row & 7);
            gload16((const char*)kr + (kbase + row) * 128 + csrc * 16,
                    (char*)Ks[buf] + (i * 256 + t) * 16);
        }
#pragma unroll
        for (int i = 0; i < 2; i++) {
            int row = i * 32 + srow;
            int csrc = sc16 ^ (row & 7);
            gload16((const char*)vt + (size_t)row * 2048 + kbase * 2 + csrc * 16,
                    (char*)Vs[buf] + (i * 256 + t) * 16);
        }
    };

    bf16x8 qf[2];
#pragma unroll
    for (int dc = 0; dc < 2; dc++)
        qf[dc] = as_bf(*(const u16x8*)&qb[(size_t)qs * HID + h * 64 + dc * 32 + 8 * lg]);

    float m_i = -1e30f, l_i = 0.0f;
    f32x4 o[4];
#pragma unroll
    for (int d4 = 0; d4 < 4; d4++) o[d4] = (f32x4)0.0f;

    stage(0, 0);
    if (nt > 1) stage(1, 1);

    for (int ti = 0; ti < nt; ti++) {
        int cur = ti & 1;
        if (ti + 1 < nt) { asm volatile("s_waitcnt vmcnt(4)" ::: "memory"); }
        else             { asm volatile("s_waitcnt vmcnt(0)" ::: "memory"); }
        __builtin_amdgcn_s_barrier();            // tile ti fully landed
        int k0 = k_lo + ti * 64;
        if (k0 < kend_w) {
            f32x4 st[4];
#pragma unroll
            for (int nc = 0; nc < 4; nc++) st[nc] = (f32x4)0.0f;
#pragma unroll
            for (int nc = 0; nc < 4; nc++) {
                int krow = nc * 16 + lr;
#pragma unroll
                for (int dc = 0; dc < 2; dc++) {
                    bf16x8 kf = as_bf(*(const u16x8*)&Ks[cur][krow * 64 + (((dc * 4 + lg) ^ sw) << 3)]);
                    st[nc] = __builtin_amdgcn_mfma_f32_16x16x32_bf16(kf, qf[dc], st[nc], 0, 0, 0);
                }
            }
            bool needmask = (k0 + 64 > j * 16);
            float mx = -1e30f;
            if (needmask) {
#pragma unroll
                for (int nc = 0; nc < 4; nc++)
#pragma unroll
                    for (int i = 0; i < 4; i++) {
                        int ks = k0 + nc * 16 + 4 * lg + i;
                        float v = (ks <= qs) ? st[nc][i] : -1e30f;
                        st[nc][i] = v;
                        mx = fmaxf(mx, v);
                    }
            } else {
#pragma unroll
                for (int nc = 0; nc < 4; nc++)
#pragma unroll
                    for (int i = 0; i < 4; i++) mx = fmaxf(mx, st[nc][i]);
            }
            mx = fmaxf(mx, __shfl_xor(mx, 16));
            mx = fmaxf(mx, __shfl_xor(mx, 32));
            // T13 defer-max: skip rescale while max grows by <= 8
            if (!__all(mx <= m_i + 8.0f)) {
                float mn = fmaxf(m_i, mx);
                float so = __expf(m_i - mn);
                l_i *= so;
#pragma unroll
                for (int d4 = 0; d4 < 4; d4++)
#pragma unroll
                    for (int i = 0; i < 4; i++) o[d4][i] *= so;
                m_i = mn;
            }
            float ps = 0.0f;
#pragma unroll
            for (int nc = 0; nc < 4; nc++)
#pragma unroll
                for (int i = 0; i < 4; i++) {
                    float v = st[nc][i];
                    float e = (!needmask || v > -1e29f) ? __expf(v - m_i) : 0.0f;
                    st[nc][i] = e;
                    ps += e;
                }
            ps += __shfl_xor(ps, 16);
            ps += __shfl_xor(ps, 32);
            l_i += ps;
            // P^T (lane-local) -> Pl[q=lr][k] (pad 72: conflict-free)
#pragma unroll
            for (int nc = 0; nc < 4; nc++) {
                *(unsigned*)&Pl[wv][lr * 72 + nc * 16 + 4 * lg]     = pk2(st[nc][0], st[nc][1]);
                *(unsigned*)&Pl[wv][lr * 72 + nc * 16 + 4 * lg + 2] = pk2(st[nc][2], st[nc][3]);
            }
            bf16x8 pb[2];
#pragma unroll
            for (int kk = 0; kk < 2; kk++)
                pb[kk] = as_bf(*(const u16x8*)&Pl[wv][lr * 72 + kk * 32 + 8 * lg]);
#pragma unroll
            for (int d4 = 0; d4 < 4; d4++) {
                int vrow = d4 * 16 + lr;
#pragma unroll
                for (int kk = 0; kk < 2; kk++) {
                    bf16x8 vf = as_bf(*(const u16x8*)&Vs[cur][vrow * 64 + (((kk * 4 + lg) ^ sw) << 3)]);
                    o[d4] = __builtin_amdgcn_mfma_f32_16x16x32_bf16(vf, pb[kk], o[d4], 0, 0, 0);
                }
            }
        }
        asm volatile("s_waitcnt lgkmcnt(0)" ::: "memory");
        __builtin_amdgcn_s_barrier();            // all waves done with buf cur
        if (ti + 2 < nt) stage(ti + 2, cur);     // overwrite buf cur
    }

    if (nch == 1) {
        float linv = 1.0f / l_i;
#pragma unroll
        for (int d4 = 0; d4 < 4; d4++) {
            u16x4 pk;
#pragma unroll
            for (int i = 0; i < 4; i++) pk[i] = f2bf(o[d4][i] * linv);
            *(u16x4*)&ctx[(size_t)qs * HID + h * 64 + d4 * 16 + 4 * lg] = pk;
        }
    } else {
        int pi = (h * 48 + (j - 16)) * 4 + c;
#pragma unroll
        for (int d4 = 0; d4 < 4; d4++) {
            u16x4 pk;
#pragma unroll
            for (int i = 0; i < 4; i++) pk[i] = f2bf(o[d4][i]);
            *(u16x4*)&Opart[(size_t)pi * 1024 + lr * 64 + d4 * 16 + 4 * lg] = pk;
        }
        if (lg == 0) MLpart[pi * 16 + lr] = make_float2(m_i, l_i);
    }
}

// ---------- split-K merge: one wave per (h, j>=16) ----------
__global__ __launch_bounds__(256) void merge_kernel(
        const unsigned short* __restrict__ Opart, const float2* __restrict__ MLpart,
        unsigned short* __restrict__ ctx) {
    int mu = blockIdx.x * 4 + (threadIdx.x >> 6);
    int lane = threadIdx.x & 63;
    int h = mu / 48, jj = mu % 48, j = 16 + jj;
    int nch = (j >> 4) + 1;
    int base = (h * 48 + jj) * 4;
    for (int q = 0; q < 16; q++) {
        float m[4], l[4], w[4];
        float M = -1e30f;
        for (int c = 0; c < nch; c++) {
            float2 ml = MLpart[(base + c) * 16 + q];
            m[c] = ml.x; l[c] = ml.y;
            M = fmaxf(M, m[c]);
        }
        float L = 0.0f;
        for (int c = 0; c < nch; c++) { w[c] = __expf(m[c] - M); L += l[c] * w[c]; }
        float acc = 0.0f;
        for (int c = 0; c < nch; c++)
            acc += w[c] * bf2f(Opart[(size_t)(base + c) * 1024 + q * 64 + lane]);
        ctx[(size_t)(j * 16 + q) * HID + h * 64 + lane] = f2bf(acc / L);
    }
}

extern "C" void kernel_launch(void* const* d_in, const int* in_sizes, int n_in,
                              void* d_out, int out_size, void* d_ws, size_t ws_size,
                              hipStream_t stream) {
    const float* hs      = (const float*)d_in[0];
    // d_in[1] = attention_mask (analytic causal mask used instead)
    const float* qkv_w   = (const float*)d_in[2];
    const float* dense_w = (const float*)d_in[3];
    float* out = (float*)d_out;

    char* ws = (char*)d_ws;
    size_t off = 0;
    auto alloc = [&](size_t bytes) -> void* {
        void* p = ws + off;
        off += (bytes + 255) & ~(size_t)255;
        return p;
    };
    unsigned short* x_bf   = (unsigned short*)alloc((size_t)S_LEN * HID * 2);    // 9.3 MB
    unsigned short* wqkvT  = (unsigned short*)alloc((size_t)NQKV * HID * 2);     // 42.5 MB
    unsigned short* q_bf   = (unsigned short*)alloc((size_t)S_LEN * HID * 2);    // 9.3 MB
    unsigned short* k_rope = (unsigned short*)alloc((size_t)S_LEN * 64 * 2);
    unsigned short* v_t    = (unsigned short*)alloc((size_t)64 * S_LEN * 2);
    unsigned short* ctx    = (unsigned short*)alloc((size_t)S_LEN * HID * 2);    // 9.3 MB
    unsigned short* wdT    = (unsigned short*)alloc((size_t)HID * HID * 2);      // 41.3 MB
    float*          cs_t   = (float*)alloc((size_t)S_LEN * 32 * 4);
    float*          sn_t   = (float*)alloc((size_t)S_LEN * 32 * 4);
    (void)ws_size;   // ~112 MB
    // Opart/MLpart alias wqkvT (dead after QKV GEMM; attn/merge run later)
    unsigned short* Opart  = wqkvT;                                   // 27.9 MB
    float2*         MLpart = (float2*)((char*)wqkvT + (size_t)71 * 48 * 4 * 1024 * 2);

    cvt_x_kernel<<<dim3(S_LEN * HID / 1024), dim3(256), 0, stream>>>(
        (const float4*)hs, (ushort4*)x_bf);
    cvt_wT_kernel<<<dim3(NQKV / 64, HID / 64), dim3(256), 0, stream>>>(
        qkv_w, wqkvT, HID, NQKV);
    cvt_wT_kernel<<<dim3(HID / 64, HID / 64), dim3(256), 0, stream>>>(
        dense_w, wdT, HID, HID);
    rope_table_kernel<<<dim3(S_LEN), dim3(32), 0, stream>>>(cs_t, sn_t);

    // QKV GEMM + fused extract/RoPE epilogue (584 = 8 XCD-chunks of 73)
    gemm_bt_kernel<1><<<dim3(NQKV / 64 * 8), dim3(256), 0, stream>>>(
        x_bf, wqkvT, q_bf, cs_t, sn_t, k_rope, v_t, HID, HID);

    attn_kernel<<<dim3(40, NH), dim3(256), 0, stream>>>(
        q_bf, k_rope, v_t, ctx, Opart, MLpart);

    merge_kernel<<<dim3(NH * 48 / 4), dim3(256), 0, stream>>>(Opart, MLpart, ctx);

    // dense GEMM (568 = 8 XCD-chunks of 71)
    gemm_bt_kernel<0><<<dim3(HID / 64 * 8), dim3(256), 0, stream>>>(
        ctx, wdT, out, nullptr, nullptr, nullptr, nullptr, HID, HID);
}